// Round 4
// baseline (8585.085 us; speedup 1.0000x reference)
//
#include <hip/hip_runtime.h>

// ---------- sizes ----------
#define BB_   2
#define LL_   2048
#define DD_   2048
#define HV_   32
#define HK_   16
#define MM_   (BB_*LL_)          // 4096 rows
#define KEYD_ 2048
#define VALD_ 4096
#define CONVD_ 8192

typedef _Float16 half8v  __attribute__((ext_vector_type(8)));
typedef _Float16 half4v  __attribute__((ext_vector_type(4)));
typedef float    f32x4   __attribute__((ext_vector_type(4)));
typedef float    f32x2   __attribute__((ext_vector_type(2)));
typedef unsigned int uint4v __attribute__((ext_vector_type(4)));

// async global->LDS DMA, 16B/lane: LDS dest = wave-uniform base + lane*16
typedef __attribute__((address_space(3))) unsigned int  u32_lds;
typedef __attribute__((address_space(1))) const unsigned int u32_glb;
__device__ __forceinline__ void async16(const _Float16* g, _Float16* l) {
    __builtin_amdgcn_global_load_lds((u32_glb*)g, (u32_lds*)l, 16, 0, 0);
}

// ===================== convert f32 -> f16 (vectorized) =====================
__global__ __launch_bounds__(256) void k_convert(const float* __restrict__ src,
                                                 _Float16* __restrict__ dst, int n4) {
    int i = blockIdx.x * 256 + threadIdx.x;
    if (i < n4) {
        f32x4 v = *(const f32x4*)(src + (size_t)i * 4);
        half4v h;
        h.x = (_Float16)v.x; h.y = (_Float16)v.y; h.z = (_Float16)v.z; h.w = (_Float16)v.w;
        *(half4v*)(dst + (size_t)i * 4) = h;
    }
}

// ============ convert + transpose: src f32 [K][N] -> dst f16 [N][K] ============
__global__ __launch_bounds__(256) void k_transpose(const float* __restrict__ src,
                                                   _Float16* __restrict__ dst, int K, int N) {
    __shared__ float tile[32][33];
    int tx = threadIdx.x & 31, ty = threadIdx.x >> 5;      // 32 x 8
    int n0 = blockIdx.x * 32, k0 = blockIdx.y * 32;
#pragma unroll
    for (int j = 0; j < 4; j++)
        tile[ty + j * 8][tx] = src[(size_t)(k0 + ty + j * 8) * N + n0 + tx];
    __syncthreads();
#pragma unroll
    for (int j = 0; j < 4; j++)
        dst[(size_t)(n0 + ty + j * 8) * K + k0 + tx] = (_Float16)tile[tx][ty + j * 8];
}

// ===================== GEMM: C[M][N] = A[M][K] * Bt[N][K]^T =====================
// f16 inputs, fp32 accumulate, 128x128 tile, BK=32, global_load_lds staging (m97-style).
template <bool OUT_F16>
__global__ __launch_bounds__(256) void k_gemm(const _Float16* __restrict__ A,
                                              const _Float16* __restrict__ Bt,
                                              void* __restrict__ Cv,
                                              int Mdim, int Ndim, int Kdim) {
    __shared__ __align__(16) _Float16 As[128 * 32];   // 8KB
    __shared__ __align__(16) _Float16 Bs[128 * 32];   // 8KB
    const int m0 = blockIdx.y * 128, n0 = blockIdx.x * 128;
    const int t = threadIdx.x;
    const int wave = t >> 6, lane = t & 63;
    const int wm = wave & 1, wn = wave >> 1;           // 2x2 waves of 64x64
    const int r16 = lane & 15, quad = lane >> 4;

    const int ci0 = wave * 64 + lane;          // [0,256)
    const int ci1 = 256 + ci0;                 // [256,512)
    const _Float16* gA0 = A  + (size_t)(m0 + (ci0 >> 2)) * Kdim + (ci0 & 3) * 8;
    const _Float16* gA1 = A  + (size_t)(m0 + (ci1 >> 2)) * Kdim + (ci1 & 3) * 8;
    const _Float16* gB0 = Bt + (size_t)(n0 + (ci0 >> 2)) * Kdim + (ci0 & 3) * 8;
    const _Float16* gB1 = Bt + (size_t)(n0 + (ci1 >> 2)) * Kdim + (ci1 & 3) * 8;
    _Float16* lA0 = As + wave * 512;
    _Float16* lA1 = As + 2048 + wave * 512;
    _Float16* lB0 = Bs + wave * 512;
    _Float16* lB1 = Bs + 2048 + wave * 512;

    f32x4 acc[4][4];
#pragma unroll
    for (int i = 0; i < 4; i++)
#pragma unroll
        for (int j = 0; j < 4; j++) acc[i][j] = (f32x4){0.f, 0.f, 0.f, 0.f};

    for (int k0 = 0; k0 < Kdim; k0 += 32) {
        async16(gA0 + k0, lA0);
        async16(gA1 + k0, lA1);
        async16(gB0 + k0, lB0);
        async16(gB1 + k0, lB1);
        __syncthreads();
        half8v af[4], bf[4];
#pragma unroll
        for (int i = 0; i < 4; i++) {
            af[i] = *(const half8v*)(&As[(wm * 64 + i * 16 + r16) * 32 + quad * 8]);
            bf[i] = *(const half8v*)(&Bs[(wn * 64 + i * 16 + r16) * 32 + quad * 8]);
        }
#pragma unroll
        for (int i = 0; i < 4; i++)
#pragma unroll
            for (int j = 0; j < 4; j++)
                acc[i][j] = __builtin_amdgcn_mfma_f32_16x16x32_f16(af[i], bf[j], acc[i][j], 0, 0, 0);
        __syncthreads();
    }
#pragma unroll
    for (int i = 0; i < 4; i++)
#pragma unroll
        for (int j = 0; j < 4; j++)
#pragma unroll
            for (int r = 0; r < 4; r++) {
                int rg = m0 + wm * 64 + i * 16 + quad * 4 + r;
                int cg = n0 + wn * 64 + j * 16 + r16;
                float v = acc[i][j][r];
                if (OUT_F16) ((_Float16*)Cv)[(size_t)rg * Ndim + cg] = (_Float16)v;
                else         ((float*)Cv)[(size_t)rg * Ndim + cg] = v;
            }
}

// ========== b/a projections (N=32 each) + beta/g activation, one row/block ==========
__global__ __launch_bounds__(256) void k_ba(const float* __restrict__ hidden,
                                            const float* __restrict__ Wb,
                                            const float* __restrict__ Wa,
                                            const float* __restrict__ dt_bias,
                                            const float* __restrict__ A_log,
                                            float* __restrict__ gout,
                                            float* __restrict__ betaout) {
    int row = blockIdx.x;
    __shared__ float xs[2048];
    __shared__ float part[4][64];
    int t = threadIdx.x;
    for (int c = t; c < 512; c += 256)
        *(f32x4*)&xs[c * 4] = *(const f32x4*)&hidden[(size_t)row * 2048 + c * 4];
    __syncthreads();
    int col = t & 63, kq = t >> 6;
    const float* W = (col < 32) ? Wb : Wa;
    int cc = col & 31;
    float p = 0.f;
#pragma unroll 4
    for (int k = kq * 512; k < kq * 512 + 512; k++)
        p += xs[k] * W[(size_t)k * 32 + cc];
    part[kq][col] = p;
    __syncthreads();
    if (t < 64) {
        float v = part[0][t] + part[1][t] + part[2][t] + part[3][t];
        if (t < 32) {
            betaout[(size_t)row * 32 + t] = 1.f / (1.f + __expf(-v));
        } else {
            int hh = t - 32;
            float x = v + dt_bias[hh];
            float sp = (x > 20.f) ? x : log1pf(__expf(x));
            gout[(size_t)row * 32 + hh] = -__expf(A_log[hh]) * sp;
        }
    }
}

// ===== causal depthwise conv (K=4) + SiLU + split + l2norm(q,k), one row/block =====
// q,k out: f32 (scan wants cvt-free f32 math); v out: f16
__global__ __launch_bounds__(256) void k_conv(const _Float16* __restrict__ mixed,
                                              const float* __restrict__ conv_w,
                                              float* __restrict__ qout,
                                              float* __restrict__ kout,
                                              _Float16* __restrict__ vout) {
    int row = blockIdx.x;
    int l = row & (LL_ - 1);
    __shared__ float yv[CONVD_];
    __shared__ float red[256];
    __shared__ float rinvs[32];
    int t = threadIdx.x;
    for (int c = t; c < CONVD_; c += 256) {
        float acc = 0.f;
#pragma unroll
        for (int j = 0; j < 4; j++) {
            int sl = l - 3 + j;          // per-sequence causal pad
            if (sl >= 0) acc += (float)mixed[(size_t)(row - 3 + j) * CONVD_ + c] * conv_w[c * 4 + j];
        }
        yv[c] = acc / (1.f + __expf(-acc));            // SiLU
    }
    __syncthreads();
    int seg = t >> 3, j8 = t & 7;
    int base = (seg < 16) ? seg * 128 : 2048 + (seg - 16) * 128;
    float ss = 0.f;
#pragma unroll
    for (int i = 0; i < 16; i++) { float vv = yv[base + j8 * 16 + i]; ss += vv * vv; }
    red[t] = ss;
    __syncthreads();
    if (t < 32) {
        float tot = 0.f;
#pragma unroll
        for (int jj = 0; jj < 8; jj++) tot += red[t * 8 + jj];
        rinvs[t] = rsqrtf(tot + 1e-6f);
    }
    __syncthreads();
    for (int c = t; c < CONVD_; c += 256) {
        float y = yv[c];
        if (c < 2048) {
            qout[(size_t)row * 2048 + c] = y * rinvs[c >> 7] * 0.08838834764831843f;
        } else if (c < 4096) {
            int c2 = c - 2048;
            kout[(size_t)row * 2048 + c2] = y * rinvs[16 + (c2 >> 7)];
        } else {
            vout[(size_t)row * 4096 + (c - 4096)] = (_Float16)y;
        }
    }
}

// ===================== gated delta-rule scan =====================
// Lane = (dvo in [0,32), dk-half in {0,1}); wave = (b, h, 32-dv quarter).
// 256 waves, 1/CU. State 64 f32/lane (float2 -> v_pk_fma_f32). ONE shfl_xor
// per reduction (the R3 profile showed 8 serial DS shuffles/step = ~960 cyc
// = the whole bottleneck). q/k stored f32: no cvt instrs on the chain.
// k/q double-buffered in VGPRs (1 step ahead); ~345 VGPR, launch_bounds(64,1).
// XCD swizzle: the 8 waves sharing a (b,hk) q/k stream have equal bid%8.
__global__ __launch_bounds__(64, 1) void k_scan(const float* __restrict__ q,
                                                const float* __restrict__ k,
                                                const _Float16* __restrict__ v,
                                                const float* __restrict__ g,
                                                const float* __restrict__ beta,
                                                _Float16* __restrict__ o) {
    int bid = blockIdx.x;          // 256 = 8 members * 32 groups
    int m = bid >> 5;              // member 0..7: (h&1)*4 + quarter
    int G = bid & 31;              // group (b,hk): bid%8 == G%8 -> same XCD
    int b = G >> 4, hk = G & 15;
    int h = hk * 2 + (m >> 2);
    int quarter = m & 3;
    int l = threadIdx.x;
    int dvo = l & 31, dkh = l >> 5;
    int dv = quarter * 32 + dvo;

    const float*    kb_ = k + ((size_t)(b * LL_) * 16 + hk) * 128 + dkh * 64;
    const float*    qb_ = q + ((size_t)(b * LL_) * 16 + hk) * 128 + dkh * 64;
    const _Float16* vb_ = v + ((size_t)(b * LL_) * 32 + h) * 128 + dv;
    const float*    gb_ = g + (size_t)(b * LL_) * 32 + h;
    const float*    bb_ = beta + (size_t)(b * LL_) * 32 + h;
    _Float16*       ob_ = o + ((size_t)(b * LL_) * 32 + h) * 128 + dv;

    f32x2 s2[32];
#pragma unroll
    for (int i = 0; i < 32; i++) s2[i] = (f32x2){0.f, 0.f};

    f32x4 kbuf[2][16], qbuf[2][16];
    float vbuf[2], gbuf[2], bbuf[2];

#define LDs(T, J)                                                         \
    do {                                                                  \
        const float* kp_ = kb_ + (size_t)(T) * 2048;                      \
        const float* qp_ = qb_ + (size_t)(T) * 2048;                      \
        _Pragma("unroll")                                                 \
        for (int c = 0; c < 16; c++) {                                    \
            kbuf[J][c] = *(const f32x4*)(kp_ + c * 4);                    \
            qbuf[J][c] = *(const f32x4*)(qp_ + c * 4);                    \
        }                                                                 \
        vbuf[J] = (float)vb_[(size_t)(T) * 4096];                        \
        gbuf[J] = gb_[(size_t)(T) * 32];                                  \
        bbuf[J] = bb_[(size_t)(T) * 32];                                  \
    } while (0)

    LDs(0, 0);
    for (int t = 0; t < LL_; t++) {
        const int cb = t & 1, nb = cb ^ 1;
        const int tn = (t + 1 < LL_) ? (t + 1) : t;
        LDs(tn, nb);                          // lands by start of step t+1

        float eg = __expf(gbuf[cb]);
        f32x2 a0 = {0.f, 0.f}, a1 = {0.f, 0.f}, a2 = {0.f, 0.f}, a3 = {0.f, 0.f};
#pragma unroll
        for (int c = 0; c < 16; c += 2) {
            a0 += kbuf[cb][c].xy     * s2[2 * c];
            a1 += kbuf[cb][c].zw     * s2[2 * c + 1];
            a2 += kbuf[cb][c + 1].xy * s2[2 * c + 2];
            a3 += kbuf[cb][c + 1].zw * s2[2 * c + 3];
        }
        f32x2 asum = (a0 + a1) + (a2 + a3);
        float kv = (asum.x + asum.y) * eg;    // kv = eg*(k . S_old)
        kv += __shfl_xor(kv, 32);             // the ONE chain shuffle
        float dlt = (vbuf[cb] - kv) * bbuf[cb];
        f32x2 eg2 = {eg, eg}, dl2 = {dlt, dlt};
        f32x2 o0 = {0.f, 0.f}, o1 = {0.f, 0.f}, o2 = {0.f, 0.f}, o3 = {0.f, 0.f};
#pragma unroll
        for (int c = 0; c < 16; c += 2) {
            s2[2 * c]     = s2[2 * c]     * eg2 + kbuf[cb][c].xy     * dl2;
            s2[2 * c + 1] = s2[2 * c + 1] * eg2 + kbuf[cb][c].zw     * dl2;
            s2[2 * c + 2] = s2[2 * c + 2] * eg2 + kbuf[cb][c + 1].xy * dl2;
            s2[2 * c + 3] = s2[2 * c + 3] * eg2 + kbuf[cb][c + 1].zw * dl2;
            o0 += qbuf[cb][c].xy     * s2[2 * c];
            o1 += qbuf[cb][c].zw     * s2[2 * c + 1];
            o2 += qbuf[cb][c + 1].xy * s2[2 * c + 2];
            o3 += qbuf[cb][c + 1].zw * s2[2 * c + 3];
        }
        f32x2 osum = (o0 + o1) + (o2 + o3);
        float ov = osum.x + osum.y;
        ov += __shfl_xor(ov, 32);             // off the s-chain
        if (l < 32) ob_[(size_t)t * 4096] = (_Float16)ov;
    }
#undef LDs
}

// ===================== gated RMSNorm, one row/block, f16 in/out =====================
__global__ __launch_bounds__(256) void k_rmsnorm(const _Float16* __restrict__ o,
                                                 const _Float16* __restrict__ z,
                                                 const float* __restrict__ norm_w,
                                                 _Float16* __restrict__ gn) {
    int row = blockIdx.x;
    __shared__ float gv[4096];
    __shared__ float red[256];
    __shared__ float rinv[32];
    int t = threadIdx.x;
    int h = t >> 3, j = t & 7;
    size_t base = (size_t)row * 4096 + h * 128 + j * 16;
    float ss = 0.f;
#pragma unroll
    for (int i = 0; i < 16; i++) {
        float ov = (float)o[base + i];
        float zv = (float)z[base + i];
        float gg = ov * zv / (1.f + __expf(-zv));
        gv[h * 128 + j * 16 + i] = gg;
        ss += gg * gg;
    }
    red[t] = ss;
    __syncthreads();
    if (t < 32) {
        float tot = 0.f;
#pragma unroll
        for (int jj = 0; jj < 8; jj++) tot += red[t * 8 + jj];
        rinv[t] = rsqrtf(tot * (1.f / 128.f) + 1e-6f);
    }
    __syncthreads();
#pragma unroll
    for (int i = 0; i < 16; i++) {
        int idx = h * 128 + j * 16 + i;
        gn[(size_t)row * 4096 + idx] = (_Float16)(gv[idx] * rinv[h] * norm_w[idx & 127]);
    }
}

// ===================== launch =====================
// Workspace (145 MB + d_out as scratch; aliases stream-ordered):
//   [  0, 16) XH f16 (r: GEMM1,GEMM2)      -> GN f16 [0,32) (w: rmsnorm after GEMM2)
//   [ 16, 48) WQKVT f16 (r: GEMM1)         -> VB f16 (w: conv, r: scan)
//   [ 48,112) MIXED f16 (w: GEMM1, r: conv)-> OB f16 [48,80) (w: scan)
//                                          -> WZT f16 [80,96)
//   [ 96,128) ZH f16 (w: GEMM2 after scan; overlaps dead MIXED tail + dead KB head)
//   [112,144) KB f32 (w: conv, r: scan)    -> WOUTT f16 [128,144) (after scan)
//   [144,145) GB + BBUF f32
//   d_out (32 MiB f32) = QB (w: conv, r: scan, overwritten by GEMM3 at end)
extern "C" void kernel_launch(void* const* d_in, const int* in_sizes, int n_in,
                              void* d_out, int out_size, void* d_ws, size_t ws_size,
                              hipStream_t stream) {
    const float* hidden  = (const float*)d_in[0];
    const float* W_qkv   = (const float*)d_in[1];
    const float* W_z     = (const float*)d_in[2];
    const float* W_b     = (const float*)d_in[3];
    const float* W_a     = (const float*)d_in[4];
    const float* conv_w  = (const float*)d_in[5];
    const float* dt_bias = (const float*)d_in[6];
    const float* A_log   = (const float*)d_in[7];
    const float* norm_w  = (const float*)d_in[8];
    const float* W_out   = (const float*)d_in[9];
    float* out = (float*)d_out;

    const size_t MB = 1ull << 20;
    char* ws = (char*)d_ws;
    if (ws_size < 146 * MB) {
        hipMemsetAsync(d_out, 0, (size_t)out_size * sizeof(float), stream);
        return;
    }

    _Float16* XH    = (_Float16*)(ws + 0 * MB);
    _Float16* WQKVT = (_Float16*)(ws + 16 * MB);
    _Float16* MIXED = (_Float16*)(ws + 48 * MB);
    float*    QB    = out;                           // d_out as q scratch
    float*    KB    = (float*)(ws + 112 * MB);
    _Float16* VB    = (_Float16*)(ws + 16 * MB);
    _Float16* OB    = (_Float16*)(ws + 48 * MB);
    _Float16* WZT   = (_Float16*)(ws + 80 * MB);
    _Float16* ZH    = (_Float16*)(ws + 96 * MB);
    _Float16* GN    = (_Float16*)(ws + 0 * MB);
    _Float16* WOUTT = (_Float16*)(ws + 128 * MB);
    float*    GB    = (float*)(ws + 144 * MB);
    float*    BBUF  = (float*)(ws + 144 * MB + 512 * 1024);

    k_convert<<<(MM_ * DD_ / 4 + 255) / 256, 256, 0, stream>>>(hidden, XH, MM_ * DD_ / 4);
    k_transpose<<<dim3(CONVD_ / 32, DD_ / 32), 256, 0, stream>>>(W_qkv, WQKVT, DD_, CONVD_);
    k_gemm<true><<<dim3(CONVD_ / 128, MM_ / 128), 256, 0, stream>>>(XH, WQKVT, MIXED, MM_, CONVD_, DD_);
    k_ba<<<MM_, 256, 0, stream>>>(hidden, W_b, W_a, dt_bias, A_log, GB, BBUF);
    k_conv<<<MM_, 256, 0, stream>>>(MIXED, conv_w, QB, KB, VB);
    k_scan<<<256, 64, 0, stream>>>(QB, KB, VB, GB, BBUF, OB);
    k_transpose<<<dim3(VALD_ / 32, DD_ / 32), 256, 0, stream>>>(W_z, WZT, DD_, VALD_);
    k_gemm<true><<<dim3(VALD_ / 128, MM_ / 128), 256, 0, stream>>>(XH, WZT, ZH, MM_, VALD_, DD_);
    k_rmsnorm<<<MM_, 256, 0, stream>>>(OB, ZH, norm_w, GN);
    k_transpose<<<dim3(DD_ / 32, VALD_ / 32), 256, 0, stream>>>(W_out, WOUTT, VALD_, DD_);
    k_gemm<false><<<dim3(DD_ / 128, MM_ / 128), 256, 0, stream>>>(GN, WOUTT, out, MM_, DD_, VALD_);
}

// Round 5
// 2454.195 us; speedup vs baseline: 3.4981x; 3.4981x over previous
//
#include <hip/hip_runtime.h>

// ---------- sizes ----------
#define BB_   2
#define LL_   2048
#define DD_   2048
#define HV_   32
#define HK_   16
#define MM_   (BB_*LL_)          // 4096 rows
#define KEYD_ 2048
#define VALD_ 4096
#define CONVD_ 8192

typedef _Float16 half8v  __attribute__((ext_vector_type(8)));
typedef _Float16 half4v  __attribute__((ext_vector_type(4)));
typedef float    f32x4   __attribute__((ext_vector_type(4)));
typedef float    f32x2   __attribute__((ext_vector_type(2)));
typedef unsigned int uint4v __attribute__((ext_vector_type(4)));

// async global->LDS DMA, 16B/lane: LDS dest = wave-uniform base + lane*16
typedef __attribute__((address_space(3))) unsigned int  u32_lds;
typedef __attribute__((address_space(1))) const unsigned int u32_glb;
__device__ __forceinline__ void async16(const _Float16* g, _Float16* l) {
    __builtin_amdgcn_global_load_lds((u32_glb*)g, (u32_lds*)l, 16, 0, 0);
}

// ===================== convert f32 -> f16 (vectorized) =====================
__global__ __launch_bounds__(256) void k_convert(const float* __restrict__ src,
                                                 _Float16* __restrict__ dst, int n4) {
    int i = blockIdx.x * 256 + threadIdx.x;
    if (i < n4) {
        f32x4 v = *(const f32x4*)(src + (size_t)i * 4);
        half4v h;
        h.x = (_Float16)v.x; h.y = (_Float16)v.y; h.z = (_Float16)v.z; h.w = (_Float16)v.w;
        *(half4v*)(dst + (size_t)i * 4) = h;
    }
}

// ============ convert + transpose: src f32 [K][N] -> dst f16 [N][K] ============
__global__ __launch_bounds__(256) void k_transpose(const float* __restrict__ src,
                                                   _Float16* __restrict__ dst, int K, int N) {
    __shared__ float tile[32][33];
    int tx = threadIdx.x & 31, ty = threadIdx.x >> 5;      // 32 x 8
    int n0 = blockIdx.x * 32, k0 = blockIdx.y * 32;
#pragma unroll
    for (int j = 0; j < 4; j++)
        tile[ty + j * 8][tx] = src[(size_t)(k0 + ty + j * 8) * N + n0 + tx];
    __syncthreads();
#pragma unroll
    for (int j = 0; j < 4; j++)
        dst[(size_t)(n0 + ty + j * 8) * K + k0 + tx] = (_Float16)tile[tx][ty + j * 8];
}

// ===================== GEMM: C[M][N] = A[M][K] * Bt[N][K]^T =====================
// f16 inputs, fp32 accumulate, 128x128 tile, BK=32, global_load_lds staging (m97-style).
template <bool OUT_F16>
__global__ __launch_bounds__(256) void k_gemm(const _Float16* __restrict__ A,
                                              const _Float16* __restrict__ Bt,
                                              void* __restrict__ Cv,
                                              int Mdim, int Ndim, int Kdim) {
    __shared__ __align__(16) _Float16 As[128 * 32];   // 8KB
    __shared__ __align__(16) _Float16 Bs[128 * 32];   // 8KB
    const int m0 = blockIdx.y * 128, n0 = blockIdx.x * 128;
    const int t = threadIdx.x;
    const int wave = t >> 6, lane = t & 63;
    const int wm = wave & 1, wn = wave >> 1;           // 2x2 waves of 64x64
    const int r16 = lane & 15, quad = lane >> 4;

    const int ci0 = wave * 64 + lane;          // [0,256)
    const int ci1 = 256 + ci0;                 // [256,512)
    const _Float16* gA0 = A  + (size_t)(m0 + (ci0 >> 2)) * Kdim + (ci0 & 3) * 8;
    const _Float16* gA1 = A  + (size_t)(m0 + (ci1 >> 2)) * Kdim + (ci1 & 3) * 8;
    const _Float16* gB0 = Bt + (size_t)(n0 + (ci0 >> 2)) * Kdim + (ci0 & 3) * 8;
    const _Float16* gB1 = Bt + (size_t)(n0 + (ci1 >> 2)) * Kdim + (ci1 & 3) * 8;
    _Float16* lA0 = As + wave * 512;
    _Float16* lA1 = As + 2048 + wave * 512;
    _Float16* lB0 = Bs + wave * 512;
    _Float16* lB1 = Bs + 2048 + wave * 512;

    f32x4 acc[4][4];
#pragma unroll
    for (int i = 0; i < 4; i++)
#pragma unroll
        for (int j = 0; j < 4; j++) acc[i][j] = (f32x4){0.f, 0.f, 0.f, 0.f};

    for (int k0 = 0; k0 < Kdim; k0 += 32) {
        async16(gA0 + k0, lA0);
        async16(gA1 + k0, lA1);
        async16(gB0 + k0, lB0);
        async16(gB1 + k0, lB1);
        __syncthreads();
        half8v af[4], bf[4];
#pragma unroll
        for (int i = 0; i < 4; i++) {
            af[i] = *(const half8v*)(&As[(wm * 64 + i * 16 + r16) * 32 + quad * 8]);
            bf[i] = *(const half8v*)(&Bs[(wn * 64 + i * 16 + r16) * 32 + quad * 8]);
        }
#pragma unroll
        for (int i = 0; i < 4; i++)
#pragma unroll
            for (int j = 0; j < 4; j++)
                acc[i][j] = __builtin_amdgcn_mfma_f32_16x16x32_f16(af[i], bf[j], acc[i][j], 0, 0, 0);
        __syncthreads();
    }
#pragma unroll
    for (int i = 0; i < 4; i++)
#pragma unroll
        for (int j = 0; j < 4; j++)
#pragma unroll
            for (int r = 0; r < 4; r++) {
                int rg = m0 + wm * 64 + i * 16 + quad * 4 + r;
                int cg = n0 + wn * 64 + j * 16 + r16;
                float v = acc[i][j][r];
                if (OUT_F16) ((_Float16*)Cv)[(size_t)rg * Ndim + cg] = (_Float16)v;
                else         ((float*)Cv)[(size_t)rg * Ndim + cg] = v;
            }
}

// ========== b/a projections (N=32 each) + beta/g activation, one row/block ==========
__global__ __launch_bounds__(256) void k_ba(const float* __restrict__ hidden,
                                            const float* __restrict__ Wb,
                                            const float* __restrict__ Wa,
                                            const float* __restrict__ dt_bias,
                                            const float* __restrict__ A_log,
                                            float* __restrict__ gout,
                                            float* __restrict__ betaout) {
    int row = blockIdx.x;
    __shared__ float xs[2048];
    __shared__ float part[4][64];
    int t = threadIdx.x;
    for (int c = t; c < 512; c += 256)
        *(f32x4*)&xs[c * 4] = *(const f32x4*)&hidden[(size_t)row * 2048 + c * 4];
    __syncthreads();
    int col = t & 63, kq = t >> 6;
    const float* W = (col < 32) ? Wb : Wa;
    int cc = col & 31;
    float p = 0.f;
#pragma unroll 4
    for (int k = kq * 512; k < kq * 512 + 512; k++)
        p += xs[k] * W[(size_t)k * 32 + cc];
    part[kq][col] = p;
    __syncthreads();
    if (t < 64) {
        float v = part[0][t] + part[1][t] + part[2][t] + part[3][t];
        if (t < 32) {
            betaout[(size_t)row * 32 + t] = 1.f / (1.f + __expf(-v));
        } else {
            int hh = t - 32;
            float x = v + dt_bias[hh];
            float sp = (x > 20.f) ? x : log1pf(__expf(x));
            gout[(size_t)row * 32 + hh] = -__expf(A_log[hh]) * sp;
        }
    }
}

// ===== causal depthwise conv (K=4) + SiLU + split + l2norm(q,k), one row/block =====
// q,k out: f32 (scan wants cvt-free f32 math); v out: f16
__global__ __launch_bounds__(256) void k_conv(const _Float16* __restrict__ mixed,
                                              const float* __restrict__ conv_w,
                                              float* __restrict__ qout,
                                              float* __restrict__ kout,
                                              _Float16* __restrict__ vout) {
    int row = blockIdx.x;
    int l = row & (LL_ - 1);
    __shared__ float yv[CONVD_];
    __shared__ float red[256];
    __shared__ float rinvs[32];
    int t = threadIdx.x;
    for (int c = t; c < CONVD_; c += 256) {
        float acc = 0.f;
#pragma unroll
        for (int j = 0; j < 4; j++) {
            int sl = l - 3 + j;          // per-sequence causal pad
            if (sl >= 0) acc += (float)mixed[(size_t)(row - 3 + j) * CONVD_ + c] * conv_w[c * 4 + j];
        }
        yv[c] = acc / (1.f + __expf(-acc));            // SiLU
    }
    __syncthreads();
    int seg = t >> 3, j8 = t & 7;
    int base = (seg < 16) ? seg * 128 : 2048 + (seg - 16) * 128;
    float ss = 0.f;
#pragma unroll
    for (int i = 0; i < 16; i++) { float vv = yv[base + j8 * 16 + i]; ss += vv * vv; }
    red[t] = ss;
    __syncthreads();
    if (t < 32) {
        float tot = 0.f;
#pragma unroll
        for (int jj = 0; jj < 8; jj++) tot += red[t * 8 + jj];
        rinvs[t] = rsqrtf(tot + 1e-6f);
    }
    __syncthreads();
    for (int c = t; c < CONVD_; c += 256) {
        float y = yv[c];
        if (c < 2048) {
            qout[(size_t)row * 2048 + c] = y * rinvs[c >> 7] * 0.08838834764831843f;
        } else if (c < 4096) {
            int c2 = c - 2048;
            kout[(size_t)row * 2048 + c2] = y * rinvs[16 + (c2 >> 7)];
        } else {
            vout[(size_t)row * 4096 + (c - 4096)] = (_Float16)y;
        }
    }
}

// ===================== gated delta-rule scan =====================
// Lane = (dvo in [0,32), dk-half in {0,1}); wave = (b, h, 32-dv quarter).
// 256 waves, 1/CU. State 64 f32/lane as f32x2 -> v_pk_fma_f32. ONE shfl_xor
// on the serial chain. R4 spilled to scratch (VGPR_Count=84, WRITE_SIZE 1.7GB)
// because buffers were indexed by runtime t&1 -> dynamic indexing forces
// scratch. Fix: unroll t-loop by 2 with NAMED buffers kA/kB (double-buffered
// k), one qQ buffer re-issued per half (q only read at half end: L2 latency
// hides under the s-update), scalars double-buffered, exp computed a half
// early off-chain. All array indices compile-time. ~290 VGPR, no spill.
__global__ __launch_bounds__(64, 1) void k_scan(const float* __restrict__ q,
                                                const float* __restrict__ k,
                                                const _Float16* __restrict__ v,
                                                const float* __restrict__ g,
                                                const float* __restrict__ beta,
                                                _Float16* __restrict__ o) {
    int bid = blockIdx.x;          // 256 = 8 members * 32 groups
    int m = bid >> 5;              // member 0..7: (h&1)*4 + quarter
    int G = bid & 31;              // group (b,hk): bid%8 == G%8 -> same XCD
    int b = G >> 4, hk = G & 15;
    int h = hk * 2 + (m >> 2);
    int quarter = m & 3;
    int l = threadIdx.x;
    int dvo = l & 31, dkh = l >> 5;
    int dv = quarter * 32 + dvo;

    const float*    kb_ = k + ((size_t)(b * LL_) * 16 + hk) * 128 + dkh * 64;
    const float*    qb_ = q + ((size_t)(b * LL_) * 16 + hk) * 128 + dkh * 64;
    const _Float16* vb_ = v + ((size_t)(b * LL_) * 32 + h) * 128 + dv;
    const float*    gb_ = g + (size_t)(b * LL_) * 32 + h;
    const float*    bb_ = beta + (size_t)(b * LL_) * 32 + h;
    _Float16*       ob_ = o + ((size_t)(b * LL_) * 32 + h) * 128 + dv;

    f32x2 s2[32];
#pragma unroll
    for (int i = 0; i < 32; i++) s2[i] = (f32x2){0.f, 0.f};

    f32x4 kA[16], kB[16], qQ[16];
    float vA, gA, bA, egA, vB, gB, bB, egB;

#define LDK(BUF, T)                                                       \
    do {                                                                  \
        const float* kp_ = kb_ + (size_t)(T) * 2048;                      \
        _Pragma("unroll")                                                 \
        for (int c = 0; c < 16; c++) BUF[c] = *(const f32x4*)(kp_ + c * 4); \
    } while (0)

#define LDQ(T)                                                            \
    do {                                                                  \
        const float* qp_ = qb_ + (size_t)(T) * 2048;                      \
        _Pragma("unroll")                                                 \
        for (int c = 0; c < 16; c++) qQ[c] = *(const f32x4*)(qp_ + c * 4); \
    } while (0)

#define LDV(T, VV, GG, BV)                                                \
    do {                                                                  \
        VV = (float)vb_[(size_t)(T) * 4096];                              \
        GG = gb_[(size_t)(T) * 32];                                       \
        BV = bb_[(size_t)(T) * 32];                                       \
    } while (0)

// step using k-buffer KBUF, precomputed EG, scalars VV/BV; MID injected
// between s-update and o-dot (computes next half's exp off-chain)
#define STEP(KBUF, EG, VV, BV, T, MID)                                    \
    do {                                                                  \
        f32x2 a0 = {0.f, 0.f}, a1 = {0.f, 0.f}, a2 = {0.f, 0.f}, a3 = {0.f, 0.f}; \
        _Pragma("unroll")                                                 \
        for (int c = 0; c < 16; c += 2) {                                 \
            a0 += KBUF[c].xy     * s2[2 * c];                             \
            a1 += KBUF[c].zw     * s2[2 * c + 1];                         \
            a2 += KBUF[c + 1].xy * s2[2 * c + 2];                         \
            a3 += KBUF[c + 1].zw * s2[2 * c + 3];                         \
        }                                                                 \
        f32x2 asum = (a0 + a1) + (a2 + a3);                               \
        float kv = (asum.x + asum.y) * EG;                                \
        kv += __shfl_xor(kv, 32);                                         \
        float dlt = (VV - kv) * BV;                                       \
        f32x2 eg2 = {EG, EG}, dl2 = {dlt, dlt};                           \
        _Pragma("unroll")                                                 \
        for (int c = 0; c < 16; c += 2) {                                 \
            s2[2 * c]     = s2[2 * c]     * eg2 + KBUF[c].xy     * dl2;   \
            s2[2 * c + 1] = s2[2 * c + 1] * eg2 + KBUF[c].zw     * dl2;   \
            s2[2 * c + 2] = s2[2 * c + 2] * eg2 + KBUF[c + 1].xy * dl2;   \
            s2[2 * c + 3] = s2[2 * c + 3] * eg2 + KBUF[c + 1].zw * dl2;   \
        }                                                                 \
        MID;                                                              \
        f32x2 o0 = {0.f, 0.f}, o1 = {0.f, 0.f}, o2 = {0.f, 0.f}, o3 = {0.f, 0.f}; \
        _Pragma("unroll")                                                 \
        for (int c = 0; c < 16; c += 2) {                                 \
            o0 += qQ[c].xy     * s2[2 * c];                               \
            o1 += qQ[c].zw     * s2[2 * c + 1];                           \
            o2 += qQ[c + 1].xy * s2[2 * c + 2];                           \
            o3 += qQ[c + 1].zw * s2[2 * c + 3];                           \
        }                                                                 \
        f32x2 osum = (o0 + o1) + (o2 + o3);                               \
        float ov = osum.x + osum.y;                                       \
        ov += __shfl_xor(ov, 32);                                         \
        if (l < 32) ob_[(size_t)(T) * 4096] = (_Float16)ov;               \
    } while (0)

    LDK(kA, 0);
    LDV(0, vA, gA, bA);
    egA = __expf(gA);
    for (int t = 0; t < LL_; t += 2) {
        const int t1 = t + 1;
        const int t2 = (t + 2 < LL_) ? t + 2 : LL_ - 1;
        // half 1: uses kA/egA/vA/bA
        LDK(kB, t1);
        LDQ(t);
        LDV(t1, vB, gB, bB);
        STEP(kA, egA, vA, bA, t, egB = __expf(gB));
        // half 2: uses kB/egB/vB/bB
        LDK(kA, t2);
        LDQ(t1);
        LDV(t2, vA, gA, bA);
        STEP(kB, egB, vB, bB, t1, egA = __expf(gA));
    }
#undef LDK
#undef LDQ
#undef LDV
#undef STEP
}

// ===================== gated RMSNorm, one row/block, f16 in/out =====================
__global__ __launch_bounds__(256) void k_rmsnorm(const _Float16* __restrict__ o,
                                                 const _Float16* __restrict__ z,
                                                 const float* __restrict__ norm_w,
                                                 _Float16* __restrict__ gn) {
    int row = blockIdx.x;
    __shared__ float gv[4096];
    __shared__ float red[256];
    __shared__ float rinv[32];
    int t = threadIdx.x;
    int h = t >> 3, j = t & 7;
    size_t base = (size_t)row * 4096 + h * 128 + j * 16;
    float ss = 0.f;
#pragma unroll
    for (int i = 0; i < 16; i++) {
        float ov = (float)o[base + i];
        float zv = (float)z[base + i];
        float gg = ov * zv / (1.f + __expf(-zv));
        gv[h * 128 + j * 16 + i] = gg;
        ss += gg * gg;
    }
    red[t] = ss;
    __syncthreads();
    if (t < 32) {
        float tot = 0.f;
#pragma unroll
        for (int jj = 0; jj < 8; jj++) tot += red[t * 8 + jj];
        rinv[t] = rsqrtf(tot * (1.f / 128.f) + 1e-6f);
    }
    __syncthreads();
#pragma unroll
    for (int i = 0; i < 16; i++) {
        int idx = h * 128 + j * 16 + i;
        gn[(size_t)row * 4096 + idx] = (_Float16)(gv[idx] * rinv[h] * norm_w[idx & 127]);
    }
}

// ===================== launch =====================
// Workspace (145 MB + d_out as scratch; aliases stream-ordered):
//   [  0, 16) XH f16 (r: GEMM1,GEMM2)      -> GN f16 [0,32) (w: rmsnorm after GEMM2)
//   [ 16, 48) WQKVT f16 (r: GEMM1)         -> VB f16 (w: conv, r: scan)
//   [ 48,112) MIXED f16 (w: GEMM1, r: conv)-> OB f16 [48,80) (w: scan)
//                                          -> WZT f16 [80,96)
//   [ 96,128) ZH f16 (w: GEMM2 after scan; overlaps dead MIXED tail + dead KB head)
//   [112,144) KB f32 (w: conv, r: scan)    -> WOUTT f16 [128,144) (after scan)
//   [144,145) GB + BBUF f32
//   d_out (32 MiB f32) = QB (w: conv, r: scan, overwritten by GEMM3 at end)
extern "C" void kernel_launch(void* const* d_in, const int* in_sizes, int n_in,
                              void* d_out, int out_size, void* d_ws, size_t ws_size,
                              hipStream_t stream) {
    const float* hidden  = (const float*)d_in[0];
    const float* W_qkv   = (const float*)d_in[1];
    const float* W_z     = (const float*)d_in[2];
    const float* W_b     = (const float*)d_in[3];
    const float* W_a     = (const float*)d_in[4];
    const float* conv_w  = (const float*)d_in[5];
    const float* dt_bias = (const float*)d_in[6];
    const float* A_log   = (const float*)d_in[7];
    const float* norm_w  = (const float*)d_in[8];
    const float* W_out   = (const float*)d_in[9];
    float* out = (float*)d_out;

    const size_t MB = 1ull << 20;
    char* ws = (char*)d_ws;
    if (ws_size < 146 * MB) {
        hipMemsetAsync(d_out, 0, (size_t)out_size * sizeof(float), stream);
        return;
    }

    _Float16* XH    = (_Float16*)(ws + 0 * MB);
    _Float16* WQKVT = (_Float16*)(ws + 16 * MB);
    _Float16* MIXED = (_Float16*)(ws + 48 * MB);
    float*    QB    = out;                           // d_out as q scratch
    float*    KB    = (float*)(ws + 112 * MB);
    _Float16* VB    = (_Float16*)(ws + 16 * MB);
    _Float16* OB    = (_Float16*)(ws + 48 * MB);
    _Float16* WZT   = (_Float16*)(ws + 80 * MB);
    _Float16* ZH    = (_Float16*)(ws + 96 * MB);
    _Float16* GN    = (_Float16*)(ws + 0 * MB);
    _Float16* WOUTT = (_Float16*)(ws + 128 * MB);
    float*    GB    = (float*)(ws + 144 * MB);
    float*    BBUF  = (float*)(ws + 144 * MB + 512 * 1024);

    k_convert<<<(MM_ * DD_ / 4 + 255) / 256, 256, 0, stream>>>(hidden, XH, MM_ * DD_ / 4);
    k_transpose<<<dim3(CONVD_ / 32, DD_ / 32), 256, 0, stream>>>(W_qkv, WQKVT, DD_, CONVD_);
    k_gemm<true><<<dim3(CONVD_ / 128, MM_ / 128), 256, 0, stream>>>(XH, WQKVT, MIXED, MM_, CONVD_, DD_);
    k_ba<<<MM_, 256, 0, stream>>>(hidden, W_b, W_a, dt_bias, A_log, GB, BBUF);
    k_conv<<<MM_, 256, 0, stream>>>(MIXED, conv_w, QB, KB, VB);
    k_scan<<<256, 64, 0, stream>>>(QB, KB, VB, GB, BBUF, OB);
    k_transpose<<<dim3(VALD_ / 32, DD_ / 32), 256, 0, stream>>>(W_z, WZT, DD_, VALD_);
    k_gemm<true><<<dim3(VALD_ / 128, MM_ / 128), 256, 0, stream>>>(XH, WZT, ZH, MM_, VALD_, DD_);
    k_rmsnorm<<<MM_, 256, 0, stream>>>(OB, ZH, norm_w, GN);
    k_transpose<<<dim3(DD_ / 32, VALD_ / 32), 256, 0, stream>>>(W_out, WOUTT, VALD_, DD_);
    k_gemm<false><<<dim3(DD_ / 128, MM_ / 128), 256, 0, stream>>>(GN, WOUTT, out, MM_, DD_, VALD_);
}

// Round 6
// 2104.458 us; speedup vs baseline: 4.0795x; 1.1662x over previous
//
#include <hip/hip_runtime.h>

// ---------- sizes ----------
#define BB_   2
#define LL_   2048
#define DD_   2048
#define HV_   32
#define HK_   16
#define MM_   (BB_*LL_)          // 4096 rows
#define KEYD_ 2048
#define VALD_ 4096
#define CONVD_ 8192

typedef _Float16 half8v  __attribute__((ext_vector_type(8)));
typedef _Float16 half4v  __attribute__((ext_vector_type(4)));
typedef float    f32x4   __attribute__((ext_vector_type(4)));
typedef float    f32x2   __attribute__((ext_vector_type(2)));
typedef unsigned int uint4v __attribute__((ext_vector_type(4)));

// async global->LDS DMA, 16B/lane: LDS dest = wave-uniform base + lane*16
typedef __attribute__((address_space(3))) unsigned int  u32_lds;
typedef __attribute__((address_space(1))) const unsigned int u32_glb;
__device__ __forceinline__ void async16(const _Float16* g, _Float16* l) {
    __builtin_amdgcn_global_load_lds((u32_glb*)g, (u32_lds*)l, 16, 0, 0);
}

// ===================== convert f32 -> f16 (vectorized) =====================
__global__ __launch_bounds__(256) void k_convert(const float* __restrict__ src,
                                                 _Float16* __restrict__ dst, int n4) {
    int i = blockIdx.x * 256 + threadIdx.x;
    if (i < n4) {
        f32x4 v = *(const f32x4*)(src + (size_t)i * 4);
        half4v h;
        h.x = (_Float16)v.x; h.y = (_Float16)v.y; h.z = (_Float16)v.z; h.w = (_Float16)v.w;
        *(half4v*)(dst + (size_t)i * 4) = h;
    }
}

// ============ convert + transpose: src f32 [K][N] -> dst f16 [N][K] ============
__global__ __launch_bounds__(256) void k_transpose(const float* __restrict__ src,
                                                   _Float16* __restrict__ dst, int K, int N) {
    __shared__ float tile[32][33];
    int tx = threadIdx.x & 31, ty = threadIdx.x >> 5;      // 32 x 8
    int n0 = blockIdx.x * 32, k0 = blockIdx.y * 32;
#pragma unroll
    for (int j = 0; j < 4; j++)
        tile[ty + j * 8][tx] = src[(size_t)(k0 + ty + j * 8) * N + n0 + tx];
    __syncthreads();
#pragma unroll
    for (int j = 0; j < 4; j++)
        dst[(size_t)(n0 + ty + j * 8) * K + k0 + tx] = (_Float16)tile[tx][ty + j * 8];
}

// ===================== GEMM: C[M][N] = A[M][K] * Bt[N][K]^T =====================
// f16 inputs, fp32 accumulate, 128x128 tile, BK=32, global_load_lds staging (m97-style).
template <bool OUT_F16>
__global__ __launch_bounds__(256) void k_gemm(const _Float16* __restrict__ A,
                                              const _Float16* __restrict__ Bt,
                                              void* __restrict__ Cv,
                                              int Mdim, int Ndim, int Kdim) {
    __shared__ __align__(16) _Float16 As[128 * 32];   // 8KB
    __shared__ __align__(16) _Float16 Bs[128 * 32];   // 8KB
    const int m0 = blockIdx.y * 128, n0 = blockIdx.x * 128;
    const int t = threadIdx.x;
    const int wave = t >> 6, lane = t & 63;
    const int wm = wave & 1, wn = wave >> 1;           // 2x2 waves of 64x64
    const int r16 = lane & 15, quad = lane >> 4;

    const int ci0 = wave * 64 + lane;          // [0,256)
    const int ci1 = 256 + ci0;                 // [256,512)
    const _Float16* gA0 = A  + (size_t)(m0 + (ci0 >> 2)) * Kdim + (ci0 & 3) * 8;
    const _Float16* gA1 = A  + (size_t)(m0 + (ci1 >> 2)) * Kdim + (ci1 & 3) * 8;
    const _Float16* gB0 = Bt + (size_t)(n0 + (ci0 >> 2)) * Kdim + (ci0 & 3) * 8;
    const _Float16* gB1 = Bt + (size_t)(n0 + (ci1 >> 2)) * Kdim + (ci1 & 3) * 8;
    _Float16* lA0 = As + wave * 512;
    _Float16* lA1 = As + 2048 + wave * 512;
    _Float16* lB0 = Bs + wave * 512;
    _Float16* lB1 = Bs + 2048 + wave * 512;

    f32x4 acc[4][4];
#pragma unroll
    for (int i = 0; i < 4; i++)
#pragma unroll
        for (int j = 0; j < 4; j++) acc[i][j] = (f32x4){0.f, 0.f, 0.f, 0.f};

    for (int k0 = 0; k0 < Kdim; k0 += 32) {
        async16(gA0 + k0, lA0);
        async16(gA1 + k0, lA1);
        async16(gB0 + k0, lB0);
        async16(gB1 + k0, lB1);
        __syncthreads();
        half8v af[4], bf[4];
#pragma unroll
        for (int i = 0; i < 4; i++) {
            af[i] = *(const half8v*)(&As[(wm * 64 + i * 16 + r16) * 32 + quad * 8]);
            bf[i] = *(const half8v*)(&Bs[(wn * 64 + i * 16 + r16) * 32 + quad * 8]);
        }
#pragma unroll
        for (int i = 0; i < 4; i++)
#pragma unroll
            for (int j = 0; j < 4; j++)
                acc[i][j] = __builtin_amdgcn_mfma_f32_16x16x32_f16(af[i], bf[j], acc[i][j], 0, 0, 0);
        __syncthreads();
    }
#pragma unroll
    for (int i = 0; i < 4; i++)
#pragma unroll
        for (int j = 0; j < 4; j++)
#pragma unroll
            for (int r = 0; r < 4; r++) {
                int rg = m0 + wm * 64 + i * 16 + quad * 4 + r;
                int cg = n0 + wn * 64 + j * 16 + r16;
                float v = acc[i][j][r];
                if (OUT_F16) ((_Float16*)Cv)[(size_t)rg * Ndim + cg] = (_Float16)v;
                else         ((float*)Cv)[(size_t)rg * Ndim + cg] = v;
            }
}

// ========== b/a projections (N=32 each) + beta/g activation, one row/block ==========
__global__ __launch_bounds__(256) void k_ba(const float* __restrict__ hidden,
                                            const float* __restrict__ Wb,
                                            const float* __restrict__ Wa,
                                            const float* __restrict__ dt_bias,
                                            const float* __restrict__ A_log,
                                            float* __restrict__ gout,
                                            float* __restrict__ betaout) {
    int row = blockIdx.x;
    __shared__ float xs[2048];
    __shared__ float part[4][64];
    int t = threadIdx.x;
    for (int c = t; c < 512; c += 256)
        *(f32x4*)&xs[c * 4] = *(const f32x4*)&hidden[(size_t)row * 2048 + c * 4];
    __syncthreads();
    int col = t & 63, kq = t >> 6;
    const float* W = (col < 32) ? Wb : Wa;
    int cc = col & 31;
    float p = 0.f;
#pragma unroll 4
    for (int k = kq * 512; k < kq * 512 + 512; k++)
        p += xs[k] * W[(size_t)k * 32 + cc];
    part[kq][col] = p;
    __syncthreads();
    if (t < 64) {
        float v = part[0][t] + part[1][t] + part[2][t] + part[3][t];
        if (t < 32) {
            betaout[(size_t)row * 32 + t] = 1.f / (1.f + __expf(-v));
        } else {
            int hh = t - 32;
            float x = v + dt_bias[hh];
            float sp = (x > 20.f) ? x : log1pf(__expf(x));
            gout[(size_t)row * 32 + hh] = -__expf(A_log[hh]) * sp;
        }
    }
}

// ===== causal depthwise conv (K=4) + SiLU + split + l2norm(q,k), one row/block =====
// q,k out: f32 (scan wants cvt-free f32 math); v out: f16
__global__ __launch_bounds__(256) void k_conv(const _Float16* __restrict__ mixed,
                                              const float* __restrict__ conv_w,
                                              float* __restrict__ qout,
                                              float* __restrict__ kout,
                                              _Float16* __restrict__ vout) {
    int row = blockIdx.x;
    int l = row & (LL_ - 1);
    __shared__ float yv[CONVD_];
    __shared__ float red[256];
    __shared__ float rinvs[32];
    int t = threadIdx.x;
    for (int c = t; c < CONVD_; c += 256) {
        float acc = 0.f;
#pragma unroll
        for (int j = 0; j < 4; j++) {
            int sl = l - 3 + j;          // per-sequence causal pad
            if (sl >= 0) acc += (float)mixed[(size_t)(row - 3 + j) * CONVD_ + c] * conv_w[c * 4 + j];
        }
        yv[c] = acc / (1.f + __expf(-acc));            // SiLU
    }
    __syncthreads();
    int seg = t >> 3, j8 = t & 7;
    int base = (seg < 16) ? seg * 128 : 2048 + (seg - 16) * 128;
    float ss = 0.f;
#pragma unroll
    for (int i = 0; i < 16; i++) { float vv = yv[base + j8 * 16 + i]; ss += vv * vv; }
    red[t] = ss;
    __syncthreads();
    if (t < 32) {
        float tot = 0.f;
#pragma unroll
        for (int jj = 0; jj < 8; jj++) tot += red[t * 8 + jj];
        rinvs[t] = rsqrtf(tot + 1e-6f);
    }
    __syncthreads();
    for (int c = t; c < CONVD_; c += 256) {
        float y = yv[c];
        if (c < 2048) {
            qout[(size_t)row * 2048 + c] = y * rinvs[c >> 7] * 0.08838834764831843f;
        } else if (c < 4096) {
            int c2 = c - 2048;
            kout[(size_t)row * 2048 + c2] = y * rinvs[16 + (c2 >> 7)];
        } else {
            vout[(size_t)row * 4096 + (c - 4096)] = (_Float16)y;
        }
    }
}

// ===================== gated delta-rule scan =====================
// R6 layout: lane = (dvo in [0,16), dkq in [0,4)); wave = (b, h, 16-dv tile).
// 512 waves (2/CU). s = 32 f32/lane. 2 shfl_xor on the chain (xor16, xor32).
// WHY: the vmcnt counter caps outstanding VMEM at 63. R5's layout needed
// 35 loads/step -> prefetch depth capped at 1.8 steps -> every step waited
// ~HBM latency (measured 1865 cyc/step, VALUBusy 8.6%). This layout needs
// 19 loads/step (8 k + 8 q + 3 scalars) -> triple-buffer (P=3, 57
// outstanding) covers ~900 cyc HBM latency. Named buffers only (R4: dynamic
// indexing -> scratch spill). ~260 VGPR.
__global__ __launch_bounds__(64, 1) void k_scan(const float* __restrict__ q,
                                                const float* __restrict__ k,
                                                const _Float16* __restrict__ v,
                                                const float* __restrict__ g,
                                                const float* __restrict__ beta,
                                                _Float16* __restrict__ o) {
    int bid = blockIdx.x;          // 512 = 16 members * 32 groups
    int member = bid >> 5;         // 0..15: (h&1)*8 + dv-tile
    int G = bid & 31;              // group (b,hk): bid%8 == G%8 -> same XCD
    int b = G >> 4, hk = G & 15;
    int h = hk * 2 + (member >> 3);
    int dvt = member & 7;
    int l = threadIdx.x;
    int dvo = l & 15, dkq = l >> 4;
    int dv = dvt * 16 + dvo;

    const float*    kb_ = k + ((size_t)(b * LL_) * 16 + hk) * 128 + dkq * 32;
    const float*    qb_ = q + ((size_t)(b * LL_) * 16 + hk) * 128 + dkq * 32;
    const _Float16* vb_ = v + ((size_t)(b * LL_) * 32 + h) * 128 + dv;
    const float*    gb_ = g + (size_t)(b * LL_) * 32 + h;
    const float*    bb_ = beta + (size_t)(b * LL_) * 32 + h;
    _Float16*       ob_ = o + ((size_t)(b * LL_) * 32 + h) * 128 + dv;

    f32x2 s2[16];
#pragma unroll
    for (int i = 0; i < 16; i++) s2[i] = (f32x2){0.f, 0.f};

    f32x4 kA[8], kB[8], kC[8], qA[8], qB[8], qC[8];
    float vA, gA, bA, vB, gB, bB, vC, gC, bC;

#define LDALL(KB_, QB_, VV, GG, BV, T)                                    \
    do {                                                                  \
        int T_ = ((T) < LL_) ? (T) : (LL_ - 1);                           \
        const float* kp_ = kb_ + (size_t)T_ * 2048;                       \
        const float* qp_ = qb_ + (size_t)T_ * 2048;                       \
        _Pragma("unroll")                                                 \
        for (int c = 0; c < 8; c++) {                                     \
            KB_[c] = *(const f32x4*)(kp_ + c * 4);                        \
            QB_[c] = *(const f32x4*)(qp_ + c * 4);                        \
        }                                                                 \
        VV = (float)vb_[(size_t)T_ * 4096];                               \
        GG = gb_[(size_t)T_ * 32];                                        \
        BV = bb_[(size_t)T_ * 32];                                        \
    } while (0)

#define STEP(KB_, QB_, VV, GG, BV, T)                                     \
    do {                                                                  \
        float eg = __expf(GG);                                            \
        f32x2 a0 = {0.f, 0.f}, a1 = {0.f, 0.f}, a2 = {0.f, 0.f}, a3 = {0.f, 0.f}; \
        _Pragma("unroll")                                                 \
        for (int c = 0; c < 8; c += 2) {                                  \
            a0 += KB_[c].xy     * s2[2 * c];                              \
            a1 += KB_[c].zw     * s2[2 * c + 1];                          \
            a2 += KB_[c + 1].xy * s2[2 * c + 2];                          \
            a3 += KB_[c + 1].zw * s2[2 * c + 3];                          \
        }                                                                 \
        f32x2 asum = (a0 + a1) + (a2 + a3);                               \
        float kv = (asum.x + asum.y) * eg;                                \
        kv += __shfl_xor(kv, 16);                                         \
        kv += __shfl_xor(kv, 32);                                         \
        float dlt = (VV - kv) * BV;                                       \
        f32x2 eg2 = {eg, eg}, dl2 = {dlt, dlt};                           \
        f32x2 o0 = {0.f, 0.f}, o1 = {0.f, 0.f}, o2 = {0.f, 0.f}, o3 = {0.f, 0.f}; \
        _Pragma("unroll")                                                 \
        for (int c = 0; c < 8; c += 2) {                                  \
            s2[2 * c]     = s2[2 * c]     * eg2 + KB_[c].xy     * dl2;    \
            s2[2 * c + 1] = s2[2 * c + 1] * eg2 + KB_[c].zw     * dl2;    \
            s2[2 * c + 2] = s2[2 * c + 2] * eg2 + KB_[c + 1].xy * dl2;    \
            s2[2 * c + 3] = s2[2 * c + 3] * eg2 + KB_[c + 1].zw * dl2;    \
            o0 += QB_[c].xy     * s2[2 * c];                              \
            o1 += QB_[c].zw     * s2[2 * c + 1];                          \
            o2 += QB_[c + 1].xy * s2[2 * c + 2];                          \
            o3 += QB_[c + 1].zw * s2[2 * c + 3];                          \
        }                                                                 \
        f32x2 osum = (o0 + o1) + (o2 + o3);                               \
        float ov = osum.x + osum.y;                                       \
        ov += __shfl_xor(ov, 16);                                         \
        ov += __shfl_xor(ov, 32);                                         \
        if (l < 16) ob_[(size_t)(T) * 4096] = (_Float16)ov;               \
    } while (0)

    LDALL(kA, qA, vA, gA, bA, 0);
    LDALL(kB, qB, vB, gB, bB, 1);
    LDALL(kC, qC, vC, gC, bC, 2);
    for (int t = 0; t < LL_; t += 3) {
        STEP(kA, qA, vA, gA, bA, t);
        LDALL(kA, qA, vA, gA, bA, t + 3);
        if (t + 1 < LL_) {
            STEP(kB, qB, vB, gB, bB, t + 1);
            LDALL(kB, qB, vB, gB, bB, t + 4);
        }
        if (t + 2 < LL_) {
            STEP(kC, qC, vC, gC, bC, t + 2);
            LDALL(kC, qC, vC, gC, bC, t + 5);
        }
    }
#undef LDALL
#undef STEP
}

// ===================== gated RMSNorm, one row/block, f16 in/out =====================
__global__ __launch_bounds__(256) void k_rmsnorm(const _Float16* __restrict__ o,
                                                 const _Float16* __restrict__ z,
                                                 const float* __restrict__ norm_w,
                                                 _Float16* __restrict__ gn) {
    int row = blockIdx.x;
    __shared__ float gv[4096];
    __shared__ float red[256];
    __shared__ float rinv[32];
    int t = threadIdx.x;
    int h = t >> 3, j = t & 7;
    size_t base = (size_t)row * 4096 + h * 128 + j * 16;
    float ss = 0.f;
#pragma unroll
    for (int i = 0; i < 16; i++) {
        float ov = (float)o[base + i];
        float zv = (float)z[base + i];
        float gg = ov * zv / (1.f + __expf(-zv));
        gv[h * 128 + j * 16 + i] = gg;
        ss += gg * gg;
    }
    red[t] = ss;
    __syncthreads();
    if (t < 32) {
        float tot = 0.f;
#pragma unroll
        for (int jj = 0; jj < 8; jj++) tot += red[t * 8 + jj];
        rinv[t] = rsqrtf(tot * (1.f / 128.f) + 1e-6f);
    }
    __syncthreads();
#pragma unroll
    for (int i = 0; i < 16; i++) {
        int idx = h * 128 + j * 16 + i;
        gn[(size_t)row * 4096 + idx] = (_Float16)(gv[idx] * rinv[h] * norm_w[idx & 127]);
    }
}

// ===================== launch =====================
// Workspace (145 MB + d_out as scratch; aliases stream-ordered):
//   [  0, 16) XH f16 (r: GEMM1,GEMM2)      -> GN f16 [0,32) (w: rmsnorm after GEMM2)
//   [ 16, 48) WQKVT f16 (r: GEMM1)         -> VB f16 (w: conv, r: scan)
//   [ 48,112) MIXED f16 (w: GEMM1, r: conv)-> OB f16 [48,80) (w: scan)
//                                          -> WZT f16 [80,96)
//   [ 96,128) ZH f16 (w: GEMM2 after scan; overlaps dead MIXED tail + dead KB head)
//   [112,144) KB f32 (w: conv, r: scan)    -> WOUTT f16 [128,144) (after scan)
//   [144,145) GB + BBUF f32
//   d_out (32 MiB f32) = QB (w: conv, r: scan, overwritten by GEMM3 at end)
extern "C" void kernel_launch(void* const* d_in, const int* in_sizes, int n_in,
                              void* d_out, int out_size, void* d_ws, size_t ws_size,
                              hipStream_t stream) {
    const float* hidden  = (const float*)d_in[0];
    const float* W_qkv   = (const float*)d_in[1];
    const float* W_z     = (const float*)d_in[2];
    const float* W_b     = (const float*)d_in[3];
    const float* W_a     = (const float*)d_in[4];
    const float* conv_w  = (const float*)d_in[5];
    const float* dt_bias = (const float*)d_in[6];
    const float* A_log   = (const float*)d_in[7];
    const float* norm_w  = (const float*)d_in[8];
    const float* W_out   = (const float*)d_in[9];
    float* out = (float*)d_out;

    const size_t MB = 1ull << 20;
    char* ws = (char*)d_ws;
    if (ws_size < 146 * MB) {
        hipMemsetAsync(d_out, 0, (size_t)out_size * sizeof(float), stream);
        return;
    }

    _Float16* XH    = (_Float16*)(ws + 0 * MB);
    _Float16* WQKVT = (_Float16*)(ws + 16 * MB);
    _Float16* MIXED = (_Float16*)(ws + 48 * MB);
    float*    QB    = out;                           // d_out as q scratch
    float*    KB    = (float*)(ws + 112 * MB);
    _Float16* VB    = (_Float16*)(ws + 16 * MB);
    _Float16* OB    = (_Float16*)(ws + 48 * MB);
    _Float16* WZT   = (_Float16*)(ws + 80 * MB);
    _Float16* ZH    = (_Float16*)(ws + 96 * MB);
    _Float16* GN    = (_Float16*)(ws + 0 * MB);
    _Float16* WOUTT = (_Float16*)(ws + 128 * MB);
    float*    GB    = (float*)(ws + 144 * MB);
    float*    BBUF  = (float*)(ws + 144 * MB + 512 * 1024);

    k_convert<<<(MM_ * DD_ / 4 + 255) / 256, 256, 0, stream>>>(hidden, XH, MM_ * DD_ / 4);
    k_transpose<<<dim3(CONVD_ / 32, DD_ / 32), 256, 0, stream>>>(W_qkv, WQKVT, DD_, CONVD_);
    k_gemm<true><<<dim3(CONVD_ / 128, MM_ / 128), 256, 0, stream>>>(XH, WQKVT, MIXED, MM_, CONVD_, DD_);
    k_ba<<<MM_, 256, 0, stream>>>(hidden, W_b, W_a, dt_bias, A_log, GB, BBUF);
    k_conv<<<MM_, 256, 0, stream>>>(MIXED, conv_w, QB, KB, VB);
    k_scan<<<512, 64, 0, stream>>>(QB, KB, VB, GB, BBUF, OB);
    k_transpose<<<dim3(VALD_ / 32, DD_ / 32), 256, 0, stream>>>(W_z, WZT, DD_, VALD_);
    k_gemm<true><<<dim3(VALD_ / 128, MM_ / 128), 256, 0, stream>>>(XH, WZT, ZH, MM_, VALD_, DD_);
    k_rmsnorm<<<MM_, 256, 0, stream>>>(OB, ZH, norm_w, GN);
    k_transpose<<<dim3(DD_ / 32, VALD_ / 32), 256, 0, stream>>>(W_out, WOUTT, VALD_, DD_);
    k_gemm<false><<<dim3(DD_ / 128, MM_ / 128), 256, 0, stream>>>(GN, WOUTT, out, MM_, DD_, VALD_);
}